// Round 3
// baseline (114.188 us; speedup 1.0000x reference)
//
#include <hip/hip_runtime.h>

#define GRID  2048
#define BLOCK 256
#define UNROLL 8

// ws layout: [0..GRID)        pos partials (f32)
//            [GRID..2*GRID)   neg partials (f32)
//            [2*GRID..3*GRID) pos counts  (u32)

__device__ __forceinline__ void proc_elem(float pv, int tv,
                                          float& posd, float& allsp, float& possp,
                                          float& cntf)
{
    float a    = fabsf(pv);
    float em   = __expf(-a);            // exp(-|p|) in (0,1]
    float lc   = __logf(1.0f + em);     // log1p(exp(-|p|)), stable
    float sp   = fmaxf(pv, 0.0f) + lc;  // softplus(p)
    float diff = sp - pv;               // softplus(-p)
    float t    = (float)tv;             // tv in {0,1}
    posd  = fmaf(t, diff, posd);        // sum over pos of softplus(-p)
    allsp += sp;                        // sum over all of softplus(p)
    possp = fmaf(t, sp, possp);         // sum over pos of softplus(p)
    cntf  += t;                         // pos count (exact: <=128 per thread? no, exact in f32 up to 2^24)
}

__global__ __launch_bounds__(BLOCK) void formicro_reduce(
    const float4* __restrict__ pred4,
    const int4*   __restrict__ ty4,
    int n4,
    const float*  __restrict__ pred_s,
    const int*    __restrict__ ty_s,
    int n,
    float* __restrict__ ws)
{
    const int T   = gridDim.x * blockDim.x;
    const int gid = blockIdx.x * blockDim.x + threadIdx.x;

    float posd = 0.f, allsp = 0.f, possp = 0.f, cntf = 0.f;

    // main unrolled loop: UNROLL (pred,label) float4/int4 pairs in flight
    const int nfull = n4 / (UNROLL * T);
    int i = gid;
    for (int g = 0; g < nfull; ++g) {
        float4 P[UNROLL];
        int4   L[UNROLL];
        // interleave issue order so consume-in-order staggers vmcnt waits
        #pragma unroll
        for (int u = 0; u < UNROLL; ++u) {
            P[u] = pred4[i + u * T];
            L[u] = ty4[i + u * T];
        }
        #pragma unroll
        for (int u = 0; u < UNROLL; ++u) {
            proc_elem(P[u].x, L[u].x, posd, allsp, possp, cntf);
            proc_elem(P[u].y, L[u].y, posd, allsp, possp, cntf);
            proc_elem(P[u].z, L[u].z, posd, allsp, possp, cntf);
            proc_elem(P[u].w, L[u].w, posd, allsp, possp, cntf);
        }
        i += UNROLL * T;
    }
    // leftover float4s (dead at N=8192^2 but kept for generality)
    for (; i < n4; i += T) {
        float4 p = pred4[i];
        int4   t = ty4[i];
        proc_elem(p.x, t.x, posd, allsp, possp, cntf);
        proc_elem(p.y, t.y, posd, allsp, possp, cntf);
        proc_elem(p.z, t.z, posd, allsp, possp, cntf);
        proc_elem(p.w, t.w, posd, allsp, possp, cntf);
    }
    // scalar tail (n % 4)
    for (int k = (n4 << 2) + gid; k < n; k += T) {
        proc_elem(pred_s[k], ty_s[k], posd, allsp, possp, cntf);
    }

    float negs = allsp - possp;   // sum over neg of softplus(p)

    // wave-64 reduction
    #pragma unroll
    for (int off = 32; off > 0; off >>= 1) {
        posd += __shfl_down(posd, off);
        negs += __shfl_down(negs, off);
        cntf += __shfl_down(cntf, off);
    }

    __shared__ float spos[BLOCK / 64];
    __shared__ float sneg[BLOCK / 64];
    __shared__ float scnt[BLOCK / 64];
    const int wid  = threadIdx.x >> 6;
    const int lane = threadIdx.x & 63;
    if (lane == 0) { spos[wid] = posd; sneg[wid] = negs; scnt[wid] = cntf; }
    __syncthreads();

    if (threadIdx.x == 0) {
        float P = 0.f, Ng = 0.f, C = 0.f;
        #pragma unroll
        for (int w = 0; w < BLOCK / 64; ++w) { P += spos[w]; Ng += sneg[w]; C += scnt[w]; }
        ws[blockIdx.x]        = P;
        ws[GRID + blockIdx.x] = Ng;
        // per-block count <= 32768, exact as u32
        ((unsigned*)ws)[2 * GRID + blockIdx.x] = (unsigned)C;
    }
}

__global__ __launch_bounds__(BLOCK) void formicro_finalize(
    const float* __restrict__ ws, float* __restrict__ out, float total)
{
    float posd = 0.f, negs = 0.f;
    unsigned cnt = 0;
    for (int i = threadIdx.x; i < GRID; i += BLOCK) {
        posd += ws[i];
        negs += ws[GRID + i];
        cnt  += ((const unsigned*)ws)[2 * GRID + i];
    }
    #pragma unroll
    for (int off = 32; off > 0; off >>= 1) {
        posd += __shfl_down(posd, off);
        negs += __shfl_down(negs, off);
        cnt  += __shfl_down(cnt, off);
    }
    __shared__ float    spos[BLOCK / 64];
    __shared__ float    sneg[BLOCK / 64];
    __shared__ unsigned scnt[BLOCK / 64];
    const int wid  = threadIdx.x >> 6;
    const int lane = threadIdx.x & 63;
    if (lane == 0) { spos[wid] = posd; sneg[wid] = negs; scnt[wid] = cnt; }
    __syncthreads();
    if (threadIdx.x == 0) {
        float P = 0.f, Ng = 0.f;
        unsigned C = 0;
        #pragma unroll
        for (int w = 0; w < BLOCK / 64; ++w) { P += spos[w]; Ng += sneg[w]; C += scnt[w]; }
        float npos = (float)C;
        float nneg = total - npos;
        out[0] = P / npos + Ng / nneg;
    }
}

extern "C" void kernel_launch(void* const* d_in, const int* in_sizes, int n_in,
                              void* d_out, int out_size, void* d_ws, size_t ws_size,
                              hipStream_t stream)
{
    const float* pred = (const float*)d_in[0];
    const int*   ty   = (const int*)d_in[1];
    float*       out  = (float*)d_out;
    float*       ws   = (float*)d_ws;

    int n  = in_sizes[0];   // 8192*8192 = 67108864
    int n4 = n >> 2;

    formicro_reduce<<<GRID, BLOCK, 0, stream>>>(
        (const float4*)pred, (const int4*)ty, n4, pred, ty, n, ws);

    formicro_finalize<<<1, BLOCK, 0, stream>>>(ws, out, (float)n);
}

// Round 4
// 109.243 us; speedup vs baseline: 1.0453x; 1.0453x over previous
//
#include <hip/hip_runtime.h>

#define GRID  2048
#define BLOCK 256
#define UNROLL 4

typedef float f4 __attribute__((ext_vector_type(4)));
typedef int   i4 __attribute__((ext_vector_type(4)));

// ws layout: [0..GRID)        pos partials (f32)
//            [GRID..2*GRID)   neg partials (f32)
//            [2*GRID..3*GRID) pos counts  (u32)

__device__ __forceinline__ void proc_elem(float pv, int tv,
                                          float& posd, float& allsp, float& possp,
                                          float& cntf)
{
    float a    = fabsf(pv);
    float em   = __expf(-a);            // exp(-|p|) in (0,1]
    float lc   = __logf(1.0f + em);     // log1p(exp(-|p|)), stable
    float sp   = fmaxf(pv, 0.0f) + lc;  // softplus(p)
    float diff = sp - pv;               // softplus(-p)
    float t    = (float)tv;             // tv in {0,1}
    posd  = fmaf(t, diff, posd);        // sum over pos of softplus(-p)
    allsp += sp;                        // sum over all of softplus(p)
    possp = fmaf(t, sp, possp);         // sum over pos of softplus(p)
    cntf  += t;
}

__global__ __launch_bounds__(BLOCK) void formicro_reduce(
    const f4* __restrict__ pred4,
    const i4* __restrict__ ty4,
    int n4,
    const float* __restrict__ pred_s,
    const int*   __restrict__ ty_s,
    int n,
    float* __restrict__ ws)
{
    const int T   = gridDim.x * blockDim.x;
    const int gid = blockIdx.x * blockDim.x + threadIdx.x;

    float posd = 0.f, allsp = 0.f, possp = 0.f, cntf = 0.f;

    const int nfull = n4 / (UNROLL * T);
    int i = gid;
    for (int g = 0; g < nfull; ++g) {
        f4 P[UNROLL];
        i4 L[UNROLL];
        #pragma unroll
        for (int u = 0; u < UNROLL; ++u) {
            // pred: non-temporal (streaming, keep it OUT of L3 so ty can own L3)
            P[u] = __builtin_nontemporal_load(&pred4[i + u * T]);
        }
        #pragma unroll
        for (int u = 0; u < UNROLL; ++u) {
            // ty: cacheable — 256 MB, exactly fits Infinity Cache
            L[u] = ty4[i + u * T];
        }
        #pragma unroll
        for (int u = 0; u < UNROLL; ++u) {
            proc_elem(P[u][0], L[u][0], posd, allsp, possp, cntf);
            proc_elem(P[u][1], L[u][1], posd, allsp, possp, cntf);
            proc_elem(P[u][2], L[u][2], posd, allsp, possp, cntf);
            proc_elem(P[u][3], L[u][3], posd, allsp, possp, cntf);
        }
        i += UNROLL * T;
    }
    // leftover float4s (dead at N=8192^2 but kept for generality)
    for (; i < n4; i += T) {
        f4 p = __builtin_nontemporal_load(&pred4[i]);
        i4 t = ty4[i];
        proc_elem(p[0], t[0], posd, allsp, possp, cntf);
        proc_elem(p[1], t[1], posd, allsp, possp, cntf);
        proc_elem(p[2], t[2], posd, allsp, possp, cntf);
        proc_elem(p[3], t[3], posd, allsp, possp, cntf);
    }
    // scalar tail (n % 4)
    for (int k = (n4 << 2) + gid; k < n; k += T) {
        proc_elem(pred_s[k], ty_s[k], posd, allsp, possp, cntf);
    }

    float negs = allsp - possp;   // sum over neg of softplus(p)

    // wave-64 reduction
    #pragma unroll
    for (int off = 32; off > 0; off >>= 1) {
        posd += __shfl_down(posd, off);
        negs += __shfl_down(negs, off);
        cntf += __shfl_down(cntf, off);
    }

    __shared__ float spos[BLOCK / 64];
    __shared__ float sneg[BLOCK / 64];
    __shared__ float scnt[BLOCK / 64];
    const int wid  = threadIdx.x >> 6;
    const int lane = threadIdx.x & 63;
    if (lane == 0) { spos[wid] = posd; sneg[wid] = negs; scnt[wid] = cntf; }
    __syncthreads();

    if (threadIdx.x == 0) {
        float P = 0.f, Ng = 0.f, C = 0.f;
        #pragma unroll
        for (int w = 0; w < BLOCK / 64; ++w) { P += spos[w]; Ng += sneg[w]; C += scnt[w]; }
        ws[blockIdx.x]        = P;
        ws[GRID + blockIdx.x] = Ng;
        ((unsigned*)ws)[2 * GRID + blockIdx.x] = (unsigned)C;  // <= 32768, exact
    }
}

__global__ __launch_bounds__(BLOCK) void formicro_finalize(
    const float* __restrict__ ws, float* __restrict__ out, float total)
{
    float posd = 0.f, negs = 0.f;
    unsigned cnt = 0;
    for (int i = threadIdx.x; i < GRID; i += BLOCK) {
        posd += ws[i];
        negs += ws[GRID + i];
        cnt  += ((const unsigned*)ws)[2 * GRID + i];
    }
    #pragma unroll
    for (int off = 32; off > 0; off >>= 1) {
        posd += __shfl_down(posd, off);
        negs += __shfl_down(negs, off);
        cnt  += __shfl_down(cnt, off);
    }
    __shared__ float    spos[BLOCK / 64];
    __shared__ float    sneg[BLOCK / 64];
    __shared__ unsigned scnt[BLOCK / 64];
    const int wid  = threadIdx.x >> 6;
    const int lane = threadIdx.x & 63;
    if (lane == 0) { spos[wid] = posd; sneg[wid] = negs; scnt[wid] = cnt; }
    __syncthreads();
    if (threadIdx.x == 0) {
        float P = 0.f, Ng = 0.f;
        unsigned C = 0;
        #pragma unroll
        for (int w = 0; w < BLOCK / 64; ++w) { P += spos[w]; Ng += sneg[w]; C += scnt[w]; }
        float npos = (float)C;
        float nneg = total - npos;
        out[0] = P / npos + Ng / nneg;
    }
}

extern "C" void kernel_launch(void* const* d_in, const int* in_sizes, int n_in,
                              void* d_out, int out_size, void* d_ws, size_t ws_size,
                              hipStream_t stream)
{
    const float* pred = (const float*)d_in[0];
    const int*   ty   = (const int*)d_in[1];
    float*       out  = (float*)d_out;
    float*       ws   = (float*)d_ws;

    int n  = in_sizes[0];   // 8192*8192 = 67108864
    int n4 = n >> 2;

    formicro_reduce<<<GRID, BLOCK, 0, stream>>>(
        (const f4*)pred, (const i4*)ty, n4, pred, ty, n, ws);

    formicro_finalize<<<1, BLOCK, 0, stream>>>(ws, out, (float)n);
}